// Round 2
// baseline (2451.940 us; speedup 1.0000x reference)
//
#include <hip/hip_runtime.h>

// ChemicalLLM: x_{t+1} = norm(relu(x + a*einsum(W,x,x))), then big decode GEMM.
//  - recur_kernel: 8 blocks (1/batch), 1024 threads (16 waves). W int8
//    register-resident: 64 dwords/lane (fits 128-VGPR cap at 4 waves/EU).
//    Single barrier/step, double-buffered partials, all-wave in-register
//    epilogue, per-row emb-max bound for x-quant scale.
//  - decode_kernel: bf16 MFMA 16x16x32, split-bf16 3-pass (~f32 accuracy),
//    write-bound (~1.05 GB out).
//  - prep: W absmax/int8 pack; Wd bf16 hi/lo split; emb row-max.

typedef unsigned int u32;
typedef unsigned short u16;
typedef __attribute__((ext_vector_type(8))) short short8;
typedef __attribute__((ext_vector_type(4))) float f32x4;

#define DECAY_ 0.1f
#define ALPHA_ 0.2f
#define EPS_ 1e-8f
#define B_ 8
#define S_ 1024
#define N_ 64
#define V_ 32000

// ---------- bf16 helpers (manual, RNE) ----------
static __device__ __forceinline__ u16 f2bf(float f) {
  u32 u = __float_as_uint(f);
  u32 r = (u + 0x7fffu + ((u >> 16) & 1u)) >> 16;
  return (u16)r;
}
static __device__ __forceinline__ float bf2f(u16 h) {
  return __uint_as_float(((u32)h) << 16);
}

// ---------- int8 dot4 ----------
#if defined(__has_builtin)
#if __has_builtin(__builtin_amdgcn_sdot4)
#define HAVE_SDOT4 1
#endif
#endif
static __device__ __forceinline__ int dot4(int a, int b, int c) {
#ifdef HAVE_SDOT4
  return __builtin_amdgcn_sdot4(a, b, c, false);
#else
  int s = c;
  s += (int)(signed char)(a) * (int)(signed char)(b);
  s += (int)(signed char)(a >> 8) * (int)(signed char)(b >> 8);
  s += (int)(signed char)(a >> 16) * (int)(signed char)(b >> 16);
  s += (int)(a >> 24) * (int)(b >> 24);
  return s;
#endif
}

static __device__ __forceinline__ float wave_max64(float v) {
#pragma unroll
  for (int m = 1; m < 64; m <<= 1) v = fmaxf(v, __shfl_xor(v, m, 64));
  return v;
}

// ---------- prep: |W| max ----------
__global__ void wmax_kernel(const float* __restrict__ W, u32* __restrict__ out) {
  int gid = blockIdx.x * blockDim.x + threadIdx.x;
  int stride = gridDim.x * blockDim.x;
  float m = 0.0f;
  for (int i = gid; i < N_ * N_ * N_; i += stride) m = fmaxf(m, fabsf(W[i]));
  m = wave_max64(m);
  if ((threadIdx.x & 63) == 0) atomicMax(out, __float_as_uint(m));  // f>=0: bits monotone
}

// ---------- prep: quantize+pack W ----------
// Wq dword idx = (j*16 + q)*64 + k packs W[4q+e][j][k] for e=0..3 (i along bytes)
__global__ void quantw_kernel(const float* __restrict__ W, const u32* __restrict__ wmaxb,
                              u32* __restrict__ Wq) {
  int idx = blockIdx.x * blockDim.x + threadIdx.x;  // 65536 threads
  float s = 127.0f / fmaxf(__uint_as_float(wmaxb[0]), 1e-30f);
  int j = idx >> 10;
  int q = (idx >> 6) & 15;
  int k = idx & 63;
  u32 pk = 0;
#pragma unroll
  for (int e = 0; e < 4; ++e) {
    float v = W[(((4 * q + e) * N_) + j) * N_ + k];
    int qi = (int)rintf(v * s);
    qi = qi > 127 ? 127 : (qi < -127 ? -127 : qi);
    pk |= ((u32)qi & 0xffu) << (8 * e);
  }
  Wq[idx] = pk;
}

// ---------- prep: Wd -> bf16 hi/lo split ----------
__global__ void wdsplit_kernel(const float* __restrict__ Wd, u16* __restrict__ hi,
                               u16* __restrict__ lo) {
  int idx = blockIdx.x * blockDim.x + threadIdx.x;  // 2048000
  float v = Wd[idx];
  u16 hb = f2bf(v);
  hi[idx] = hb;
  lo[idx] = f2bf(v - bf2f(hb));
}

// ---------- prep: emb row max (bound for x-quant scale) ----------
__global__ void rowmax_kernel(const float* __restrict__ emb, float* __restrict__ rmax) {
  int v = blockIdx.x * 4 + (threadIdx.x >> 6);
  int lane = threadIdx.x & 63;
  float m = wave_max64(emb[(size_t)v * N_ + lane]);
  if (lane == 0) rmax[v] = fmaxf(m, 0.0f);  // max of relu(row)
}

// ---------- the serial recurrence: 1 block per batch, 16 waves ----------
__global__ __launch_bounds__(1024, 4) void recur_kernel(
    const int* __restrict__ ids, const float* __restrict__ emb,
    const u32* __restrict__ Wq, const u32* __restrict__ wmaxb,
    const float* __restrict__ rmax,
    u16* __restrict__ hs_hi, u16* __restrict__ hs_lo, float* __restrict__ outHT) {
  const int b = blockIdx.x;
  const int lane = threadIdx.x & 63;  // k in dot phase, i/k elsewhere
  const int w = threadIdx.x >> 6;     // wave 0..15, owns j in [4w, 4w+4)

  __shared__ float part[2][1024];     // [buf][w*64+lane], 8 KB

  const float sW = __uint_as_float(wmaxb[0]) * (1.0f / 127.0f);

  // W register-resident: lane l holds Wq dword for (j=4w+r, iblock=q, k=l)
  u32 wreg[64];
#pragma unroll
  for (int r = 0; r < 4; ++r) {
#pragma unroll
    for (int q = 0; q < 16; ++q)
      wreg[r * 16 + q] = Wq[(((4 * w + r) * 16 + q) << 6) + lane];
  }

  // ---- init state (all waves redundant, all in registers) ----
  int id0 = ids[b * S_];
  float xk = fmaxf(emb[(size_t)id0 * N_ + lane], 0.0f);  // x_0 (h_0 = 0)
  float bnd = fmaxf(rmax[id0], 1e-20f);                  // exact max of x_0
  float smul = bnd * (1.0f / 127.0f) * sW;
  u32 pk;
  {
    float inv = 127.0f / bnd;
    float u = xk * inv;
    float u0 = __shfl(u, (lane & 15) * 4 + 0, 64);
    float u1 = __shfl(u, (lane & 15) * 4 + 1, 64);
    float u2 = __shfl(u, (lane & 15) * 4 + 2, 64);
    float u3 = __shfl(u, (lane & 15) * 4 + 3, 64);
    pk = (u32)(int)rintf(u0) | ((u32)(int)rintf(u1) << 8) |
         ((u32)(int)rintf(u2) << 16) | ((u32)(int)rintf(u3) << 24);
  }
  int id1 = ids[b * S_ + 1];
  float pend_emb = emb[(size_t)id1 * N_ + lane];
  float pend_bnd = rmax[id1];
  int pend_id = ids[b * S_ + 2];

  for (int t = 0; t < S_; ++t) {
    // ---- dot phase: partial iact for this wave's 4 j's ----
    int xr[16];  // wave-uniform (SGPR) packed xq
#pragma unroll
    for (int q = 0; q < 16; ++q) xr[q] = __builtin_amdgcn_readlane((int)pk, q);
    float pf = 0.0f;
#pragma unroll
    for (int r = 0; r < 4; ++r) {
      int a = 0;
#pragma unroll
      for (int q = 0; q < 16; ++q) a = dot4(xr[q], (int)wreg[r * 16 + q], a);
      float xj = __uint_as_float(
          __builtin_amdgcn_readlane(__float_as_uint(xk), 4 * w + r));  // exact f32 x_j
      pf += (float)a * xj;
    }
    part[t & 1][(w << 6) | lane] = pf * smul;
    __syncthreads();

    // ---- epilogue (all waves, redundant, in-register) ----
    float p[16];
#pragma unroll
    for (int q = 0; q < 16; ++q) p[q] = part[t & 1][(q << 6) | lane];
#pragma unroll
    for (int st = 8; st >= 1; st >>= 1) {
#pragma unroll
      for (int q2 = 0; q2 < 8; ++q2)
        if (q2 < st) p[q2] += p[q2 + st];
    }
    float xact = fmaxf(fmaf(ALPHA_, p[0], xk), 0.0f);
    // interleaved sum+max reduce (independent chains overlap)
    float s = xact, mx = xact;
#pragma unroll
    for (int m = 1; m < 64; m <<= 1) {
      s += __shfl_xor(s, m, 64);
      mx = fmaxf(mx, __shfl_xor(mx, m, 64));
    }
    float rS = 1.0f / (s + EPS_);
    float h = xact * rS;

    if (w == 0) {
      int mrow = b * S_ + t;
      u16 hb = f2bf(h);
      hs_hi[(size_t)mrow * N_ + lane] = hb;
      hs_lo[(size_t)mrow * N_ + lane] = f2bf(h - bf2f(hb));
      if (t == S_ - 1) outHT[b * N_ + lane] = h;
    }

    // next state: x_{t+1} = 0.9 h + relu(emb_{t+1})
    float wn = fmaxf(pend_emb, 0.0f);
    float xn = fmaf(1.0f - DECAY_, h, wn);
    // bound on max(xn): 0.9*max(h) + max(relu(emb row))  (<= 2x actual max)
    float nbnd = fmaxf(fmaf((1.0f - DECAY_) * rS, mx, pend_bnd), 1e-20f);
    float inv = 127.0f / nbnd;
    float u = xn * inv;
    float u0 = __shfl(u, (lane & 15) * 4 + 0, 64);
    float u1 = __shfl(u, (lane & 15) * 4 + 1, 64);
    float u2 = __shfl(u, (lane & 15) * 4 + 2, 64);
    float u3 = __shfl(u, (lane & 15) * 4 + 3, 64);
    pk = (u32)(int)rintf(u0) | ((u32)(int)rintf(u1) << 8) |
         ((u32)(int)rintf(u2) << 16) | ((u32)(int)rintf(u3) << 24);
    smul = nbnd * (1.0f / 127.0f) * sW;
    xk = xn;

    // prefetch for t+2
    if (t + 2 < S_) {
      pend_emb = emb[(size_t)pend_id * N_ + lane];
      pend_bnd = rmax[pend_id];
      pend_id = ids[b * S_ + ((t + 3 < S_) ? (t + 3) : (S_ - 1))];
    }
    // single barrier per step: part[] is double-buffered, rest is registers
  }
}

// ---------- decode: logits = hs @ Wd^T + bd, split-bf16 3-pass MFMA ----------
__global__ __launch_bounds__(256) void decode_kernel(
    const u16* __restrict__ hs_hi, const u16* __restrict__ hs_lo,
    const u16* __restrict__ wd_hi, const u16* __restrict__ wd_lo,
    const float* __restrict__ bd, float* __restrict__ out) {
  const int lane = threadIdx.x & 63;
  const int w = threadIdx.x >> 6;          // 4 waves, each 16 M-rows
  const int n0 = blockIdx.x * 64;          // V block
  const int m0 = blockIdx.y * 64 + w * 16; // M rows for this wave
  const int row = m0 + (lane & 15);
  const int kg = (lane >> 4) * 8;

  short8 ah0 = *(const short8*)(hs_hi + (size_t)row * N_ + kg);
  short8 ah1 = *(const short8*)(hs_hi + (size_t)row * N_ + 32 + kg);
  short8 al0 = *(const short8*)(hs_lo + (size_t)row * N_ + kg);
  short8 al1 = *(const short8*)(hs_lo + (size_t)row * N_ + 32 + kg);

#pragma unroll
  for (int nt = 0; nt < 4; ++nt) {
    int v = n0 + nt * 16 + (lane & 15);
    short8 bh0 = *(const short8*)(wd_hi + (size_t)v * N_ + kg);
    short8 bh1 = *(const short8*)(wd_hi + (size_t)v * N_ + 32 + kg);
    short8 bl0 = *(const short8*)(wd_lo + (size_t)v * N_ + kg);
    short8 bl1 = *(const short8*)(wd_lo + (size_t)v * N_ + 32 + kg);
    float bdv = bd[v];
    f32x4 acc = {bdv, bdv, bdv, bdv};
    acc = __builtin_amdgcn_mfma_f32_16x16x32_bf16(ah0, bh0, acc, 0, 0, 0);
    acc = __builtin_amdgcn_mfma_f32_16x16x32_bf16(ah1, bh1, acc, 0, 0, 0);
    acc = __builtin_amdgcn_mfma_f32_16x16x32_bf16(ah0, bl0, acc, 0, 0, 0);
    acc = __builtin_amdgcn_mfma_f32_16x16x32_bf16(ah1, bl1, acc, 0, 0, 0);
    acc = __builtin_amdgcn_mfma_f32_16x16x32_bf16(al0, bh0, acc, 0, 0, 0);
    acc = __builtin_amdgcn_mfma_f32_16x16x32_bf16(al1, bh1, acc, 0, 0, 0);
#pragma unroll
    for (int i = 0; i < 4; ++i) {
      int r = m0 + (lane >> 4) * 4 + i;
      out[(size_t)r * V_ + v] = acc[i];
    }
  }
}

// ---------- launch ----------
extern "C" void kernel_launch(void* const* d_in, const int* in_sizes, int n_in,
                              void* d_out, int out_size, void* d_ws, size_t ws_size,
                              hipStream_t stream) {
  const int* ids = (const int*)d_in[0];
  const float* emb = (const float*)d_in[1];
  const float* W = (const float*)d_in[2];
  const float* Wd = (const float*)d_in[3];
  const float* bd = (const float*)d_in[4];
  float* out = (float*)d_out;
  char* ws = (char*)d_ws;

  // ws layout (bytes):
  // [Wq 262144][wmax 64][rowmax 128000][hs_hi 1 MiB][hs_lo 1 MiB][wd_hi 4096000][wd_lo 4096000]
  u32* Wq = (u32*)(ws);
  u32* wmax = (u32*)(ws + 262144);
  float* rmax = (float*)(ws + 262208);
  u16* hs_hi = (u16*)(ws + 390208);
  u16* hs_lo = (u16*)(ws + 1438784);
  u16* wd_hi = (u16*)(ws + 2487360);
  u16* wd_lo = (u16*)(ws + 6583360);

  hipMemsetAsync(wmax, 0, 4, stream);
  hipLaunchKernelGGL(wmax_kernel, dim3(256), dim3(256), 0, stream, W, wmax);
  hipLaunchKernelGGL(quantw_kernel, dim3(256), dim3(256), 0, stream, W, wmax, Wq);
  hipLaunchKernelGGL(rowmax_kernel, dim3(V_ / 4), dim3(256), 0, stream, emb, rmax);
  hipLaunchKernelGGL(wdsplit_kernel, dim3(8000), dim3(256), 0, stream, Wd, wd_hi, wd_lo);
  hipLaunchKernelGGL(recur_kernel, dim3(B_), dim3(1024), 0, stream, ids, emb, Wq, wmax,
                     rmax, hs_hi, hs_lo, out + (size_t)B_ * S_ * V_);
  hipLaunchKernelGGL(decode_kernel, dim3(V_ / 64, (B_ * S_) / 64), dim3(256), 0, stream,
                     hs_hi, hs_lo, wd_hi, wd_lo, bd, out);

  (void)in_sizes; (void)n_in; (void)out_size; (void)ws_size;
}

// Round 3
// 1889.791 us; speedup vs baseline: 1.2975x; 1.2975x over previous
//
#include <hip/hip_runtime.h>

// ChemicalLLM: x_{t+1} = norm(relu(x + a*einsum(W,x,x))), then big decode GEMM.
//  - recur_kernel: 8 blocks (1/batch), 512 threads (8 waves). W int8
//    register-resident: 128 dwords/lane. amdgpu_waves_per_eu(2,2) pins the
//    allocator to a 256-VGPR budget so wreg CANNOT be spilled for occupancy
//    (R1/R2 failure mode: allocator targeted high occupancy, spilled W).
//    2 barriers/step, wave0-only epilogue, raw partials in LDS.
//  - decode_kernel: bf16 MFMA 16x16x32, split-bf16 3-pass (~f32 accuracy),
//    write-bound (~1.05 GB out).
//  - prep: W absmax/int8 pack; Wd bf16 hi/lo split; emb row-max bound.

typedef unsigned int u32;
typedef unsigned short u16;
typedef __attribute__((ext_vector_type(8))) short short8;
typedef __attribute__((ext_vector_type(4))) float f32x4;

#define DECAY_ 0.1f
#define ALPHA_ 0.2f
#define EPS_ 1e-8f
#define B_ 8
#define S_ 1024
#define N_ 64
#define V_ 32000

// ---------- bf16 helpers (manual, RNE) ----------
static __device__ __forceinline__ u16 f2bf(float f) {
  u32 u = __float_as_uint(f);
  u32 r = (u + 0x7fffu + ((u >> 16) & 1u)) >> 16;
  return (u16)r;
}
static __device__ __forceinline__ float bf2f(u16 h) {
  return __uint_as_float(((u32)h) << 16);
}

// ---------- int8 dot4 ----------
#if defined(__has_builtin)
#if __has_builtin(__builtin_amdgcn_sdot4)
#define HAVE_SDOT4 1
#endif
#endif
static __device__ __forceinline__ int dot4(int a, int b, int c) {
#ifdef HAVE_SDOT4
  return __builtin_amdgcn_sdot4(a, b, c, false);
#else
  int s = c;
  s += (int)(signed char)(a) * (int)(signed char)(b);
  s += (int)(signed char)(a >> 8) * (int)(signed char)(b >> 8);
  s += (int)(signed char)(a >> 16) * (int)(signed char)(b >> 16);
  s += (int)(a >> 24) * (int)(b >> 24);
  return s;
#endif
}

static __device__ __forceinline__ float wave_max64(float v) {
#pragma unroll
  for (int m = 1; m < 64; m <<= 1) v = fmaxf(v, __shfl_xor(v, m, 64));
  return v;
}

// ---------- prep: |W| max ----------
__global__ void wmax_kernel(const float* __restrict__ W, u32* __restrict__ out) {
  int gid = blockIdx.x * blockDim.x + threadIdx.x;
  int stride = gridDim.x * blockDim.x;
  float m = 0.0f;
  for (int i = gid; i < N_ * N_ * N_; i += stride) m = fmaxf(m, fabsf(W[i]));
  m = wave_max64(m);
  if ((threadIdx.x & 63) == 0) atomicMax(out, __float_as_uint(m));  // f>=0: bits monotone
}

// ---------- prep: quantize+pack W ----------
// Wq dword idx = (j*16 + q)*64 + k packs W[4q+e][j][k] for e=0..3 (i along bytes)
__global__ void quantw_kernel(const float* __restrict__ W, const u32* __restrict__ wmaxb,
                              u32* __restrict__ Wq) {
  int idx = blockIdx.x * blockDim.x + threadIdx.x;  // 65536 threads
  float s = 127.0f / fmaxf(__uint_as_float(wmaxb[0]), 1e-30f);
  int j = idx >> 10;
  int q = (idx >> 6) & 15;
  int k = idx & 63;
  u32 pk = 0;
#pragma unroll
  for (int e = 0; e < 4; ++e) {
    float v = W[(((4 * q + e) * N_) + j) * N_ + k];
    int qi = (int)rintf(v * s);
    qi = qi > 127 ? 127 : (qi < -127 ? -127 : qi);
    pk |= ((u32)qi & 0xffu) << (8 * e);
  }
  Wq[idx] = pk;
}

// ---------- prep: Wd -> bf16 hi/lo split ----------
__global__ void wdsplit_kernel(const float* __restrict__ Wd, u16* __restrict__ hi,
                               u16* __restrict__ lo) {
  int idx = blockIdx.x * blockDim.x + threadIdx.x;  // 2048000
  float v = Wd[idx];
  u16 hb = f2bf(v);
  hi[idx] = hb;
  lo[idx] = f2bf(v - bf2f(hb));
}

// ---------- prep: emb row max (bound for x-quant scale) ----------
__global__ void rowmax_kernel(const float* __restrict__ emb, float* __restrict__ rmax) {
  int v = blockIdx.x * 4 + (threadIdx.x >> 6);
  int lane = threadIdx.x & 63;
  float m = wave_max64(emb[(size_t)v * N_ + lane]);
  if (lane == 0) rmax[v] = fmaxf(m, 0.0f);  // max of relu(row)
}

// ---------- the serial recurrence: 1 block per batch, 8 waves ----------
__global__ __launch_bounds__(512) __attribute__((amdgpu_waves_per_eu(2, 2)))
void recur_kernel(
    const int* __restrict__ ids, const float* __restrict__ emb,
    const u32* __restrict__ Wq, const u32* __restrict__ wmaxb,
    const float* __restrict__ rmax,
    u16* __restrict__ hs_hi, u16* __restrict__ hs_lo, float* __restrict__ outHT) {
  const int b = blockIdx.x;
  const int lane = threadIdx.x & 63;  // k in dot phase
  const int w = threadIdx.x >> 6;     // wave 0..7, owns j in [8w, 8w+8)

  __shared__ float part[8 * 64];  // raw partials (unscaled)
  __shared__ float xf_lds[N_];    // current x (f32, exact)
  __shared__ u32 xq_lds[16];      // current x quantized u8, packed 4/dword along i

  const float sW = __uint_as_float(wmaxb[0]) * (1.0f / 127.0f);

  // W register-resident: lane l holds Wq dword for (j=8w+r, iblock=q, k=l)
  u32 wreg[128];
#pragma unroll
  for (int r = 0; r < 8; ++r) {
#pragma unroll
    for (int q = 0; q < 16; ++q)
      wreg[r * 16 + q] = Wq[(((8 * w + r) * 16 + q) << 6) + lane];
  }

  // wave0-private state
  float xk = 0.0f, smul = 0.0f, pend_emb = 0.0f, pend_bnd = 0.0f;
  int pend_id = 0;

  if (w == 0) {
    int id0 = ids[b * S_];
    xk = fmaxf(emb[(size_t)id0 * N_ + lane], 0.0f);  // x_0 (h_0 = 0)
    float bnd = fmaxf(rmax[id0], 1e-20f);            // exact max of x_0
    smul = bnd * (1.0f / 127.0f) * sW;
    float inv = 127.0f / bnd;
    float u = xk * inv;
    float u0 = __shfl(u, (lane & 15) * 4 + 0, 64);
    float u1 = __shfl(u, (lane & 15) * 4 + 1, 64);
    float u2 = __shfl(u, (lane & 15) * 4 + 2, 64);
    float u3 = __shfl(u, (lane & 15) * 4 + 3, 64);
    xf_lds[lane] = xk;
    if (lane < 16) {
      xq_lds[lane] = (u32)(int)rintf(u0) | ((u32)(int)rintf(u1) << 8) |
                     ((u32)(int)rintf(u2) << 16) | ((u32)(int)rintf(u3) << 24);
    }
    int id1 = ids[b * S_ + 1];
    pend_emb = emb[(size_t)id1 * N_ + lane];
    pend_bnd = rmax[id1];
    pend_id = ids[b * S_ + 2];
  }
  __syncthreads();

  for (int t = 0; t < S_; ++t) {
    // ---- dot phase (all 8 waves): raw partial for this wave's 8 j's ----
    u32 pkv = xq_lds[lane & 15];
    int xr[16];
#pragma unroll
    for (int q = 0; q < 16; ++q) xr[q] = __builtin_amdgcn_readlane((int)pkv, q);
    float pf = 0.0f;
#pragma unroll
    for (int r = 0; r < 8; ++r) {
      int a = 0;
#pragma unroll
      for (int q = 0; q < 16; ++q) a = dot4(xr[q], (int)wreg[r * 16 + q], a);
      pf += (float)a * xf_lds[8 * w + r];  // xf uniform read, exact f32 x_j
    }
    part[(w << 6) | lane] = pf;
    __syncthreads();  // barrier A

    // ---- epilogue (wave0 only) ----
    if (w == 0) {
      float iact = 0.0f;
#pragma unroll
      for (int q = 0; q < 8; ++q) iact += part[(q << 6) | lane];
      float xact = fmaxf(fmaf(ALPHA_ * smul, iact, xk), 0.0f);
      // interleaved sum+max reduce (independent chains overlap)
      float s = xact, mx = xact;
#pragma unroll
      for (int m = 1; m < 64; m <<= 1) {
        s += __shfl_xor(s, m, 64);
        mx = fmaxf(mx, __shfl_xor(mx, m, 64));
      }
      float rS = 1.0f / (s + EPS_);
      float h = xact * rS;

      int mrow = b * S_ + t;
      u16 hb = f2bf(h);
      hs_hi[(size_t)mrow * N_ + lane] = hb;
      hs_lo[(size_t)mrow * N_ + lane] = f2bf(h - bf2f(hb));
      if (t == S_ - 1) outHT[b * N_ + lane] = h;

      // next state: x_{t+1} = 0.9 h + relu(emb_{t+1})
      float wn = fmaxf(pend_emb, 0.0f);
      float xn = fmaf(1.0f - DECAY_, h, wn);
      // bound on max(xn): 0.9*max(h) + max(relu(emb row))  (<= 2x actual)
      float nbnd = fmaxf(fmaf((1.0f - DECAY_) * rS, mx, pend_bnd), 1e-20f);
      float inv = 127.0f / nbnd;
      float u = xn * inv;
      float u0 = __shfl(u, (lane & 15) * 4 + 0, 64);
      float u1 = __shfl(u, (lane & 15) * 4 + 1, 64);
      float u2 = __shfl(u, (lane & 15) * 4 + 2, 64);
      float u3 = __shfl(u, (lane & 15) * 4 + 3, 64);
      xf_lds[lane] = xn;
      if (lane < 16) {
        xq_lds[lane] = (u32)(int)rintf(u0) | ((u32)(int)rintf(u1) << 8) |
                       ((u32)(int)rintf(u2) << 16) | ((u32)(int)rintf(u3) << 24);
      }
      smul = nbnd * (1.0f / 127.0f) * sW;
      xk = xn;

      // prefetch for t+2
      if (t + 2 < S_) {
        pend_emb = emb[(size_t)pend_id * N_ + lane];
        pend_bnd = rmax[pend_id];
        pend_id = ids[b * S_ + ((t + 3 < S_) ? (t + 3) : (S_ - 1))];
      }
    }
    __syncthreads();  // barrier B
  }
}

// ---------- decode: logits = hs @ Wd^T + bd, split-bf16 3-pass MFMA ----------
__global__ __launch_bounds__(256) void decode_kernel(
    const u16* __restrict__ hs_hi, const u16* __restrict__ hs_lo,
    const u16* __restrict__ wd_hi, const u16* __restrict__ wd_lo,
    const float* __restrict__ bd, float* __restrict__ out) {
  const int lane = threadIdx.x & 63;
  const int w = threadIdx.x >> 6;          // 4 waves, each 16 M-rows
  const int n0 = blockIdx.x * 64;          // V block
  const int m0 = blockIdx.y * 64 + w * 16; // M rows for this wave
  const int row = m0 + (lane & 15);
  const int kg = (lane >> 4) * 8;

  short8 ah0 = *(const short8*)(hs_hi + (size_t)row * N_ + kg);
  short8 ah1 = *(const short8*)(hs_hi + (size_t)row * N_ + 32 + kg);
  short8 al0 = *(const short8*)(hs_lo + (size_t)row * N_ + kg);
  short8 al1 = *(const short8*)(hs_lo + (size_t)row * N_ + 32 + kg);

#pragma unroll
  for (int nt = 0; nt < 4; ++nt) {
    int v = n0 + nt * 16 + (lane & 15);
    short8 bh0 = *(const short8*)(wd_hi + (size_t)v * N_ + kg);
    short8 bh1 = *(const short8*)(wd_hi + (size_t)v * N_ + 32 + kg);
    short8 bl0 = *(const short8*)(wd_lo + (size_t)v * N_ + kg);
    short8 bl1 = *(const short8*)(wd_lo + (size_t)v * N_ + 32 + kg);
    float bdv = bd[v];
    f32x4 acc = {bdv, bdv, bdv, bdv};
    acc = __builtin_amdgcn_mfma_f32_16x16x32_bf16(ah0, bh0, acc, 0, 0, 0);
    acc = __builtin_amdgcn_mfma_f32_16x16x32_bf16(ah1, bh1, acc, 0, 0, 0);
    acc = __builtin_amdgcn_mfma_f32_16x16x32_bf16(ah0, bl0, acc, 0, 0, 0);
    acc = __builtin_amdgcn_mfma_f32_16x16x32_bf16(ah1, bl1, acc, 0, 0, 0);
    acc = __builtin_amdgcn_mfma_f32_16x16x32_bf16(al0, bh0, acc, 0, 0, 0);
    acc = __builtin_amdgcn_mfma_f32_16x16x32_bf16(al1, bh1, acc, 0, 0, 0);
#pragma unroll
    for (int i = 0; i < 4; ++i) {
      int r = m0 + (lane >> 4) * 4 + i;
      out[(size_t)r * V_ + v] = acc[i];
    }
  }
}

// ---------- launch ----------
extern "C" void kernel_launch(void* const* d_in, const int* in_sizes, int n_in,
                              void* d_out, int out_size, void* d_ws, size_t ws_size,
                              hipStream_t stream) {
  const int* ids = (const int*)d_in[0];
  const float* emb = (const float*)d_in[1];
  const float* W = (const float*)d_in[2];
  const float* Wd = (const float*)d_in[3];
  const float* bd = (const float*)d_in[4];
  float* out = (float*)d_out;
  char* ws = (char*)d_ws;

  // ws layout (bytes):
  // [Wq 262144][wmax 64][rowmax 128000][hs_hi 1 MiB][hs_lo 1 MiB][wd_hi 4096000][wd_lo 4096000]
  u32* Wq = (u32*)(ws);
  u32* wmax = (u32*)(ws + 262144);
  float* rmax = (float*)(ws + 262208);
  u16* hs_hi = (u16*)(ws + 390208);
  u16* hs_lo = (u16*)(ws + 1438784);
  u16* wd_hi = (u16*)(ws + 2487360);
  u16* wd_lo = (u16*)(ws + 6583360);

  hipMemsetAsync(wmax, 0, 4, stream);
  hipLaunchKernelGGL(wmax_kernel, dim3(256), dim3(256), 0, stream, W, wmax);
  hipLaunchKernelGGL(quantw_kernel, dim3(256), dim3(256), 0, stream, W, wmax, Wq);
  hipLaunchKernelGGL(rowmax_kernel, dim3(V_ / 4), dim3(256), 0, stream, emb, rmax);
  hipLaunchKernelGGL(wdsplit_kernel, dim3(8000), dim3(256), 0, stream, Wd, wd_hi, wd_lo);
  hipLaunchKernelGGL(recur_kernel, dim3(B_), dim3(512), 0, stream, ids, emb, Wq, wmax,
                     rmax, hs_hi, hs_lo, out + (size_t)B_ * S_ * V_);
  hipLaunchKernelGGL(decode_kernel, dim3(V_ / 64, (B_ * S_) / 64), dim3(256), 0, stream,
                     hs_hi, hs_lo, wd_hi, wd_lo, bd, out);

  (void)in_sizes; (void)n_in; (void)out_size; (void)ws_size;
}